// Round 7
// baseline (345.182 us; speedup 1.0000x reference)
//
#include <hip/hip_runtime.h>

// CustomGraphConv (fp32 in/out, int64 edge_index runtime-detected):
//   msg[e,o] = sum_{a,i} ea[e,a]*W[a,o,i]*x[src_e,i]; scatter-add to dst; relu(+bias).
//
// R6 counters proved stage2 is bound by device-scope f32 atomic rate (25.6M atomics
// = 113 us invariant across rounds, traffic-only floor would be 62 us). This version
// ELIMINATES the per-(edge,channel) atomics via counting-sort by dst (CSR):
//   k_init:      zero histogram; block 0 detects int64 edge_index
//   k_hist:      cnt[dst]++            (1.6M atomics on 400 KB, L2-resident)
//   k_scan1/2:   exclusive prefix sum -> off[], cur[]=off[]
//   k_scatter:   edge records [src int32 | ea bf16 x8] into dst-sorted order
//   k_aggregate: 16 lanes/node: T[a,i] += ea[a]*x[src,i] (rank-factored outer
//                product), contract with W (LDS), fused bias+relu, ONE write/node.
// No y tensor, no stage1, no atomic accumulation into out.
// ws need ~33.6 MB (known >= 51.3 MB from R3 running the old path-A).

#define IN_C 16
#define OUT_C 16
#define NA 8

typedef unsigned short u16;
typedef unsigned int u32;

__device__ __forceinline__ float bfbits(u32 hi) {
    union { u32 u; float f; } c; c.u = hi; return c.f;
}
__device__ __forceinline__ u16 f2bf(float f) {
    union { float f; u32 u; } c; c.f = f;
    u32 u = c.u + (0x7fffu + ((c.u >> 16) & 1u));   // RNE
    return (u16)(u >> 16);
}

// ---------- init: zero cnt[]; block 0 detects int64 (odd dwords all zero) ----------
__global__ void __launch_bounds__(256) k_init(
    const int* __restrict__ ei, long long E, int* __restrict__ flag,
    int* __restrict__ cnt, int n_nodes) {
    int k = blockIdx.x * 256 + threadIdx.x;
    if (k < n_nodes) cnt[k] = 0;
    if (blockIdx.x == 0) {
        __shared__ int s_nz;
        if (threadIdx.x == 0) s_nz = 0;
        __syncthreads();
        long long step = (E / 256) | 1;
        long long pos = 1 + 2 * (long long)threadIdx.x * step;
        if (pos < 2 * E && ei[pos] != 0) atomicOr(&s_nz, 1);
        __syncthreads();
        if (threadIdx.x == 0) flag[0] = (s_nz == 0) ? 1 : 0;   // 1 => int64
    }
}

// ---------- histogram of dst ----------
__global__ void __launch_bounds__(256) k_hist(
    const int* __restrict__ ei, long long E, const int* __restrict__ flag,
    int* __restrict__ cnt) {
    long long e = (long long)blockIdx.x * 256 + threadIdx.x;
    if (e >= E) return;
    int dst = flag[0] ? ei[2 * (E + e)] : ei[E + e];
    atomicAdd(&cnt[dst], 1);
}

// ---------- scan (two-level, 1024/block) ----------
__global__ void __launch_bounds__(1024) k_scan1(
    const int* __restrict__ cnt, int n, int* __restrict__ off, int* __restrict__ aux) {
    __shared__ int s[1024];
    int t = threadIdx.x;
    int gid = blockIdx.x * 1024 + t;
    int c = (gid < n) ? cnt[gid] : 0;
    s[t] = c;
    __syncthreads();
    for (int d = 1; d < 1024; d <<= 1) {
        int v = (t >= d) ? s[t - d] : 0;
        __syncthreads();
        s[t] += v;
        __syncthreads();
    }
    if (gid < n) off[gid] = s[t] - c;          // exclusive within block
    if (t == 1023) aux[blockIdx.x] = s[1023];  // block total
}

__global__ void __launch_bounds__(1024) k_scan2(
    int* __restrict__ off, int* __restrict__ cur, const int* __restrict__ aux,
    int nblk, int n) {
    __shared__ int s_aux[128];
    __shared__ int s_pfx;
    if (threadIdx.x < 128) s_aux[threadIdx.x] = (threadIdx.x < nblk) ? aux[threadIdx.x] : 0;
    __syncthreads();
    if (threadIdx.x == 0) {
        int p = 0;
        for (int j = 0; j < (int)blockIdx.x; ++j) p += s_aux[j];
        s_pfx = p;
    }
    __syncthreads();
    int gid = blockIdx.x * 1024 + threadIdx.x;
    if (gid < n) {
        int o = off[gid] + s_pfx;
        off[gid] = o;
        cur[gid] = o;   // scatter cursor; after scatter, cur[n] == row end
    }
}

// ---------- scatter edge records into dst-sorted order ----------
__global__ void __launch_bounds__(256) k_scatter(
    const int* __restrict__ ei, const float* __restrict__ ea,
    const int* __restrict__ flag, int* __restrict__ cur,
    int* __restrict__ p_src, uint4* __restrict__ p_ea, long long E) {
    long long e = (long long)blockIdx.x * 256 + threadIdx.x;
    if (e >= E) return;
    int src, dst;
    if (flag[0]) { src = ei[2 * e]; dst = ei[2 * (E + e)]; }
    else         { src = ei[e];     dst = ei[E + e]; }
    const float4* ap = reinterpret_cast<const float4*>(ea + e * NA);
    float4 a0 = ap[0], a1 = ap[1];
    union { uint4 u; u16 h[8]; } pk;
    pk.h[0] = f2bf(a0.x); pk.h[1] = f2bf(a0.y); pk.h[2] = f2bf(a0.z); pk.h[3] = f2bf(a0.w);
    pk.h[4] = f2bf(a1.x); pk.h[5] = f2bf(a1.y); pk.h[6] = f2bf(a1.z); pk.h[7] = f2bf(a1.w);
    int pos = atomicAdd(&cur[dst], 1);
    p_src[pos] = src;
    p_ea[pos] = pk.u;
}

// ---------- aggregate: 16 lanes/node, T[a,i] outer-product accumulate,
//            W-contraction via LDS transpose, fused bias+relu ----------
__global__ void __launch_bounds__(256) k_aggregate(
    const float* __restrict__ x, const float* __restrict__ W,
    const float* __restrict__ bias,
    const int* __restrict__ off, const int* __restrict__ cur,
    const int* __restrict__ p_src, const uint4* __restrict__ p_ea,
    float* __restrict__ out, int n_nodes) {
    __shared__ float Wl[2048];       // W[a][o][i] flat: a*256 + o*16 + i
    __shared__ float P[16 * 272];    // per-group transpose buffer, stride 17
    for (int k = threadIdx.x; k < 2048; k += 256) Wl[k] = W[k];
    __syncthreads();

    int g = threadIdx.x >> 4;        // group (node slot) within block
    int i = threadIdx.x & 15;        // lane role: input channel, then output channel
    int n = blockIdx.x * 16 + g;

    float T0 = 0.f, T1 = 0.f, T2 = 0.f, T3 = 0.f, T4 = 0.f, T5 = 0.f, T6 = 0.f, T7 = 0.f;
    float bi = bias[i];
    if (n < n_nodes) {
        int s = off[n], e = cur[n];
        for (int p = s; p < e; ++p) {
            int src = p_src[p];            // uniform within group -> broadcast
            uint4 eu = p_ea[p];            // uniform within group
            float xv = x[(size_t)src * IN_C + i];   // 16 lanes: coalesced 64 B
            T0 = fmaf(bfbits(eu.x << 16),         xv, T0);
            T1 = fmaf(bfbits(eu.x & 0xffff0000u), xv, T1);
            T2 = fmaf(bfbits(eu.y << 16),         xv, T2);
            T3 = fmaf(bfbits(eu.y & 0xffff0000u), xv, T3);
            T4 = fmaf(bfbits(eu.z << 16),         xv, T4);
            T5 = fmaf(bfbits(eu.z & 0xffff0000u), xv, T5);
            T6 = fmaf(bfbits(eu.w << 16),         xv, T6);
            T7 = fmaf(bfbits(eu.w & 0xffff0000u), xv, T7);
        }
    }
    // partial[o] = sum_a W[a,o,i] * T[a]   (lane i holds column i of T)
    float* Pg = P + g * 272;
#pragma unroll
    for (int o = 0; o < 16; ++o) {
        const float* w = Wl + o * 16 + i;
        float pv = T0 * w[0];
        pv = fmaf(T1, w[256],  pv);
        pv = fmaf(T2, w[512],  pv);
        pv = fmaf(T3, w[768],  pv);
        pv = fmaf(T4, w[1024], pv);
        pv = fmaf(T5, w[1280], pv);
        pv = fmaf(T6, w[1536], pv);
        pv = fmaf(T7, w[1792], pv);
        Pg[i * 17 + o] = pv;     // stride-17: conflict-free (<=2-way, free)
    }
    __syncthreads();
    // lane i now plays role of output channel o=i: sum over input lanes l
    float sum = 0.f;
#pragma unroll
    for (int l = 0; l < 16; ++l) sum += Pg[l * 17 + i];
    if (n < n_nodes) out[(size_t)n * OUT_C + i] = fmaxf(sum + bi, 0.f);
}

// =======================================================================
// Fallback path (smaller ws): R6-proven factorized y-bf16 + atomic stage2
// =======================================================================
__device__ __forceinline__ float dot4(float4 a, float4 b) {
    float s = a.x * b.x;
    s = fmaf(a.y, b.y, s); s = fmaf(a.z, b.z, s); s = fmaf(a.w, b.w, s);
    return s;
}

__global__ void __launch_bounds__(256) k_stage1(
    const float* __restrict__ x, const float* __restrict__ W,
    const int* __restrict__ ei, long long n_edges,
    u16* __restrict__ y, float* __restrict__ out,
    int* __restrict__ flag, int n_nodes) {
    __shared__ int s_nz;
    if (blockIdx.x == 0) {
        if (threadIdx.x == 0) s_nz = 0;
        __syncthreads();
        long long step = (n_edges / 256) | 1;
        long long pos = 1 + 2 * (long long)threadIdx.x * step;
        if (pos < 2 * n_edges && ei[pos] != 0) atomicOr(&s_nz, 1);
        __syncthreads();
        if (threadIdx.x == 0) flag[0] = (s_nz == 0) ? 1 : 0;
    }
    __shared__ float4 Wl[OUT_C][33];
    for (int k = threadIdx.x; k < 512; k += 256) {
        int a = k >> 6, o = (k >> 2) & 15, q = k & 3;
        Wl[o][a * 4 + q] = reinterpret_cast<const float4*>(W)[k];
    }
    __syncthreads();
    int npairs = (n_nodes + 1) >> 1;
    int idx = blockIdx.x * 256 + threadIdx.x;
    if (idx >= npairs * OUT_C) return;
    int p = idx >> 4, o = idx & 15;
    int n0 = p * 2;
    bool has1 = (n0 + 1) < n_nodes;
    const float4* xp0 = reinterpret_cast<const float4*>(x + (size_t)n0 * IN_C);
    float4 X0[4] = {xp0[0], xp0[1], xp0[2], xp0[3]};
    float4 X1[4];
    if (has1) {
        const float4* xp1 = reinterpret_cast<const float4*>(x + (size_t)(n0 + 1) * IN_C);
        X1[0] = xp1[0]; X1[1] = xp1[1]; X1[2] = xp1[2]; X1[3] = xp1[3];
    }
    union { uint4 u; u16 h[8]; } pk0, pk1;
#pragma unroll
    for (int a = 0; a < NA; ++a) {
        float4 w0 = Wl[o][a * 4 + 0], w1 = Wl[o][a * 4 + 1];
        float4 w2 = Wl[o][a * 4 + 2], w3 = Wl[o][a * 4 + 3];
        float s0 = dot4(w0, X0[0]) + dot4(w1, X0[1]) + dot4(w2, X0[2]) + dot4(w3, X0[3]);
        pk0.h[a] = f2bf(s0);
        if (has1) {
            float s1 = dot4(w0, X1[0]) + dot4(w1, X1[1]) + dot4(w2, X1[2]) + dot4(w3, X1[3]);
            pk1.h[a] = f2bf(s1);
        }
    }
    reinterpret_cast<uint4*>(y + ((size_t)n0 * OUT_C + o) * NA)[0] = pk0.u;
    out[(size_t)n0 * OUT_C + o] = 0.f;
    if (has1) {
        reinterpret_cast<uint4*>(y + ((size_t)(n0 + 1) * OUT_C + o) * NA)[0] = pk1.u;
        out[(size_t)(n0 + 1) * OUT_C + o] = 0.f;
    }
}

__global__ void __launch_bounds__(256) k_stage2(
    const int* __restrict__ ei, const float* __restrict__ ea,
    const u16* __restrict__ y, float* __restrict__ out,
    const int* __restrict__ flag, long long n_edges) {
    long long idx = (long long)blockIdx.x * 256 + threadIdx.x;
    if (idx >= n_edges * OUT_C) return;
    long long e = idx >> 4;
    int o = (int)(idx & 15);
    int src, dst;
    if (flag[0]) { src = ei[2 * e]; dst = ei[2 * (n_edges + e)]; }
    else         { src = ei[e];     dst = ei[n_edges + e]; }
    const float4* ap = reinterpret_cast<const float4*>(ea + e * NA);
    float4 a0 = ap[0], a1 = ap[1];
    uint4 yu = reinterpret_cast<const uint4*>(y + ((size_t)src * OUT_C + o) * NA)[0];
    float s = bfbits(yu.x << 16) * a0.x;
    s = fmaf(bfbits(yu.x & 0xffff0000u), a0.y, s);
    s = fmaf(bfbits(yu.y << 16),         a0.z, s);
    s = fmaf(bfbits(yu.y & 0xffff0000u), a0.w, s);
    s = fmaf(bfbits(yu.z << 16),         a1.x, s);
    s = fmaf(bfbits(yu.z & 0xffff0000u), a1.y, s);
    s = fmaf(bfbits(yu.w << 16),         a1.z, s);
    s = fmaf(bfbits(yu.w & 0xffff0000u), a1.w, s);
    unsafeAtomicAdd(out + (size_t)dst * OUT_C + o, s);
}

__global__ void __launch_bounds__(256) k_bias_relu(
    const float* __restrict__ bias, float* __restrict__ out, int total4) {
    int idx = blockIdx.x * 256 + threadIdx.x;
    if (idx >= total4) return;
    int j0 = (idx & 3) * 4;
    const float4 b = reinterpret_cast<const float4*>(bias + j0)[0];
    float4* op = reinterpret_cast<float4*>(out) + idx;
    float4 v = op[0];
    v.x = fmaxf(v.x + b.x, 0.f);
    v.y = fmaxf(v.y + b.y, 0.f);
    v.z = fmaxf(v.z + b.z, 0.f);
    v.w = fmaxf(v.w + b.w, 0.f);
    op[0] = v;
}

__global__ void __launch_bounds__(256) k_direct(
    const float* __restrict__ x, const int* __restrict__ ei,
    const float* __restrict__ ea, const float* __restrict__ W,
    float* __restrict__ out, long long n_edges) {
    __shared__ float Wl[OUT_C][129];
    for (int k = threadIdx.x; k < NA * OUT_C * IN_C; k += 256) {
        int a = k >> 8, o = (k >> 4) & 15, i = k & 15;
        Wl[o][a * IN_C + i] = W[k];
    }
    __syncthreads();
    long long idx = (long long)blockIdx.x * 256 + threadIdx.x;
    if (idx >= n_edges * OUT_C) return;
    long long e = idx >> 4;
    int o = (int)(idx & 15);
    int src = ei[2 * e], dst = ei[2 * (n_edges + e)];
    const float4* ap = reinterpret_cast<const float4*>(ea + e * NA);
    float4 a0 = ap[0], a1 = ap[1];
    float av[NA] = {a0.x, a0.y, a0.z, a0.w, a1.x, a1.y, a1.z, a1.w};
    const float4* xp = reinterpret_cast<const float4*>(x + (size_t)src * IN_C);
    float4 x0 = xp[0], x1 = xp[1], x2 = xp[2], x3 = xp[3];
    float xv[16] = {x0.x, x0.y, x0.z, x0.w, x1.x, x1.y, x1.z, x1.w,
                    x2.x, x2.y, x2.z, x2.w, x3.x, x3.y, x3.z, x3.w};
    float s = 0.f;
#pragma unroll
    for (int a = 0; a < NA; ++a) {
        float d = 0.f;
#pragma unroll
        for (int i = 0; i < IN_C; ++i) d = fmaf(Wl[o][a * IN_C + i], xv[i], d);
        s = fmaf(av[a], d, s);
    }
    unsafeAtomicAdd(out + (size_t)dst * OUT_C + o, s);
}

static inline size_t a256(size_t v) { return (v + 255) & ~(size_t)255; }

extern "C" void kernel_launch(void* const* d_in, const int* in_sizes, int n_in,
                              void* d_out, int out_size, void* d_ws, size_t ws_size,
                              hipStream_t stream) {
    const float* x    = (const float*)d_in[0];   // [N,16] f32
    const int*   ei   = (const int*)d_in[1];     // [2,E] int64/int32 (runtime-detected)
    const float* ea   = (const float*)d_in[2];   // [E,8] f32
    const float* W    = (const float*)d_in[3];   // [8,16,16] f32
    const float* bias = (const float*)d_in[4];   // [16] f32
    float* out = (float*)d_out;

    int n_nodes = in_sizes[0] / IN_C;
    long long E = in_sizes[2] / NA;

    // ws layout for CSR path
    size_t o_flag = 0;
    size_t o_cnt  = 256;
    size_t o_off  = o_cnt + a256((size_t)n_nodes * 4);
    size_t o_cur  = o_off + a256((size_t)n_nodes * 4);
    size_t o_aux  = o_cur + a256((size_t)n_nodes * 4);
    size_t o_psrc = o_aux + 1024;
    size_t o_pea  = o_psrc + a256((size_t)E * 4);
    size_t total  = o_pea + a256((size_t)E * 16);

    int gE = (int)((E + 255) / 256);
    int gN = (n_nodes + 255) / 256;
    int nblk_scan = (n_nodes + 1023) / 1024;

    if (ws_size >= total) {
        char* w8 = (char*)d_ws;
        int*   flag  = (int*)(w8 + o_flag);
        int*   cnt   = (int*)(w8 + o_cnt);
        int*   off   = (int*)(w8 + o_off);
        int*   cur   = (int*)(w8 + o_cur);
        int*   aux   = (int*)(w8 + o_aux);
        int*   p_src = (int*)(w8 + o_psrc);
        uint4* p_ea  = (uint4*)(w8 + o_pea);

        k_init<<<gN, 256, 0, stream>>>(ei, E, flag, cnt, n_nodes);
        k_hist<<<gE, 256, 0, stream>>>(ei, E, flag, cnt);
        k_scan1<<<nblk_scan, 1024, 0, stream>>>(cnt, n_nodes, off, aux);
        k_scan2<<<nblk_scan, 1024, 0, stream>>>(off, cur, aux, nblk_scan, n_nodes);
        k_scatter<<<gE, 256, 0, stream>>>(ei, ea, flag, cur, p_src, p_ea, E);
        k_aggregate<<<(n_nodes + 15) / 16, 256, 0, stream>>>(
            x, W, bias, off, cur, p_src, p_ea, out, n_nodes);
    } else {
        size_t y_bytes = (size_t)n_nodes * OUT_C * NA * sizeof(u16);  // 25.6 MB
        if (ws_size >= 64 + y_bytes) {
            int* flag = (int*)d_ws;
            u16* y = (u16*)((char*)d_ws + 64);
            int npairs = (n_nodes + 1) >> 1;
            int t1 = npairs * OUT_C;
            k_stage1<<<(t1 + 255) / 256, 256, 0, stream>>>(x, W, ei, E, y, out, flag, n_nodes);
            long long tE = E * OUT_C;
            k_stage2<<<(int)((tE + 255) / 256), 256, 0, stream>>>(ei, ea, y, out, flag, E);
        } else {
            hipMemsetAsync(d_out, 0, (size_t)n_nodes * OUT_C * sizeof(float), stream);
            long long tE = E * OUT_C;
            k_direct<<<(int)((tE + 255) / 256), 256, 0, stream>>>(x, ei, ea, W, out, E);
        }
        int t4 = (n_nodes * OUT_C) / 4;
        k_bias_relu<<<(t4 + 255) / 256, 256, 0, stream>>>(bias, out, t4);
    }
}

// Round 8
// 200.062 us; speedup vs baseline: 1.7254x; 1.7254x over previous
//
#include <hip/hip_runtime.h>

// CustomGraphConv (fp32 in/out, int64 edge_index runtime-detected):
//   msg[e,o] = sum_{a,i} ea[e,a]*W[a,o,i]*x[src_e,i]; scatter-add to dst; relu(+bias).
//
// Structure (R6-derived; R7 proved CSR/sort loses to atomics on this HW):
//   stage1: y[n,o,a] = sum_i W[a,o,i]*x[n,i]  (bf16, 25.6 MB, L3-resident)
//   stage2: 8 lanes/edge; lane q computes channels {2q,2q+1} via dot8 against
//           y[src], packs bf16x2, ONE global_atomic_pk_add_bf16 -> 12.8M lane-ops
//           (vs 25.6M f32 atomics = the measured 113-us floor in R4/R6).
//           Accumulation split across two bf16 buffers by edge parity to halve
//           the bf16 running-sum rounding walk.
//   final:  out = relu(f32(bufA) + f32(bufB) + bias), single write of d_out.

#define IN_C 16
#define OUT_C 16
#define NA 8

typedef unsigned short u16;
typedef unsigned int u32;
typedef short v2s __attribute__((ext_vector_type(2)));

__device__ __forceinline__ float bfbits(u32 hi) {
    union { u32 u; float f; } c; c.u = hi; return c.f;
}
__device__ __forceinline__ u16 f2bf(float f) {
    union { float f; u32 u; } c; c.f = f;
    u32 u = c.u + (0x7fffu + ((c.u >> 16) & 1u));   // RNE
    return (u16)(u >> 16);
}
__device__ __forceinline__ float dot4(float4 a, float4 b) {
    float s = a.x * b.x;
    s = fmaf(a.y, b.y, s); s = fmaf(a.z, b.z, s); s = fmaf(a.w, b.w, s);
    return s;
}
__device__ __forceinline__ float dot8y(uint4 yu, float4 a0, float4 a1) {
    float s = bfbits(yu.x << 16) * a0.x;
    s = fmaf(bfbits(yu.x & 0xffff0000u), a0.y, s);
    s = fmaf(bfbits(yu.y << 16),         a0.z, s);
    s = fmaf(bfbits(yu.y & 0xffff0000u), a0.w, s);
    s = fmaf(bfbits(yu.z << 16),         a1.x, s);
    s = fmaf(bfbits(yu.z & 0xffff0000u), a1.y, s);
    s = fmaf(bfbits(yu.w << 16),         a1.z, s);
    s = fmaf(bfbits(yu.w & 0xffff0000u), a1.w, s);
    return s;
}

// ---------- stage 1: y_bf16[n][o][a] = dot(W[a,o,:], x[n,:]), 2 nodes/thread;
//            zeroes out[] (harmless in pk path); block 0 detects int64 ----------
__global__ void __launch_bounds__(256) k_stage1(
    const float* __restrict__ x, const float* __restrict__ W,
    const int* __restrict__ ei, long long n_edges,
    u16* __restrict__ y, float* __restrict__ out,
    int* __restrict__ flag, int n_nodes) {
    __shared__ int s_nz;
    if (blockIdx.x == 0) {
        if (threadIdx.x == 0) s_nz = 0;
        __syncthreads();
        long long step = (n_edges / 256) | 1;
        long long pos = 1 + 2 * (long long)threadIdx.x * step;
        if (pos < 2 * n_edges && ei[pos] != 0) atomicOr(&s_nz, 1);
        __syncthreads();
        if (threadIdx.x == 0) flag[0] = (s_nz == 0) ? 1 : 0;   // 1 => int64
    }
    __shared__ float4 Wl[OUT_C][33];
    for (int k = threadIdx.x; k < 512; k += 256) {
        int a = k >> 6, o = (k >> 2) & 15, q = k & 3;
        Wl[o][a * 4 + q] = reinterpret_cast<const float4*>(W)[k];
    }
    __syncthreads();
    int npairs = (n_nodes + 1) >> 1;
    int idx = blockIdx.x * 256 + threadIdx.x;
    if (idx >= npairs * OUT_C) return;
    int p = idx >> 4, o = idx & 15;
    int n0 = p * 2;
    bool has1 = (n0 + 1) < n_nodes;
    const float4* xp0 = reinterpret_cast<const float4*>(x + (size_t)n0 * IN_C);
    float4 X0[4] = {xp0[0], xp0[1], xp0[2], xp0[3]};
    float4 X1[4];
    if (has1) {
        const float4* xp1 = reinterpret_cast<const float4*>(x + (size_t)(n0 + 1) * IN_C);
        X1[0] = xp1[0]; X1[1] = xp1[1]; X1[2] = xp1[2]; X1[3] = xp1[3];
    }
    union { uint4 u; u16 h[8]; } pk0, pk1;
#pragma unroll
    for (int a = 0; a < NA; ++a) {
        float4 w0 = Wl[o][a * 4 + 0], w1 = Wl[o][a * 4 + 1];
        float4 w2 = Wl[o][a * 4 + 2], w3 = Wl[o][a * 4 + 3];
        float s0 = dot4(w0, X0[0]) + dot4(w1, X0[1]) + dot4(w2, X0[2]) + dot4(w3, X0[3]);
        pk0.h[a] = f2bf(s0);
        if (has1) {
            float s1 = dot4(w0, X1[0]) + dot4(w1, X1[1]) + dot4(w2, X1[2]) + dot4(w3, X1[3]);
            pk1.h[a] = f2bf(s1);
        }
    }
    reinterpret_cast<uint4*>(y + ((size_t)n0 * OUT_C + o) * NA)[0] = pk0.u;
    out[(size_t)n0 * OUT_C + o] = 0.f;
    if (has1) {
        reinterpret_cast<uint4*>(y + ((size_t)(n0 + 1) * OUT_C + o) * NA)[0] = pk1.u;
        out[(size_t)(n0 + 1) * OUT_C + o] = 0.f;
    }
}

// ---------- stage 2 (pk-bf16): 8 lanes/edge, lane q -> channels 2q,2q+1,
//            one packed-bf16 atomic per lane; edge-parity buffer split ----------
__global__ void __launch_bounds__(256) k_stage2_pk(
    const int* __restrict__ ei, const float* __restrict__ ea,
    const u16* __restrict__ y, u16* __restrict__ bufA, u16* __restrict__ bufB,
    const int* __restrict__ flag, long long n_edges) {
    long long gid = (long long)blockIdx.x * 256 + threadIdx.x;
    if (gid >= n_edges * 8) return;
    long long e = gid >> 3;
    int q = (int)(gid & 7);          // channel pair: 2q, 2q+1
    int src, dst;
    if (flag[0]) { src = ei[2 * e]; dst = ei[2 * (n_edges + e)]; }
    else         { src = ei[e];     dst = ei[n_edges + e]; }

    const float4* ap = reinterpret_cast<const float4*>(ea + e * NA);
    float4 a0 = ap[0], a1 = ap[1];

    // y rows for channels 2q and 2q+1: 32 B contiguous; lanes q=0..7 tile the 256 B row.
    const uint4* yp = reinterpret_cast<const uint4*>(y + ((size_t)src * OUT_C + 2 * q) * NA);
    float s0 = dot8y(yp[0], a0, a1);
    float s1 = dot8y(yp[1], a0, a1);

    union { v2s v; u16 h[2]; } pk;
    pk.h[0] = f2bf(s0);
    pk.h[1] = f2bf(s1);
    u16* target = (e & 1) ? bufB : bufA;
    v2s* addr = reinterpret_cast<v2s*>(target + (size_t)dst * OUT_C + 2 * q);
    __builtin_amdgcn_global_atomic_fadd_v2bf16(addr, pk.v);
}

// ---------- final (pk path): out = relu(f32(bufA)+f32(bufB)+bias), 8 ch/thread ----------
__global__ void __launch_bounds__(256) k_final_pk(
    const u16* __restrict__ bufA, const u16* __restrict__ bufB,
    const float* __restrict__ bias, float* __restrict__ out, int total8) {
    int idx = blockIdx.x * 256 + threadIdx.x;
    if (idx >= total8) return;
    uint4 ua = reinterpret_cast<const uint4*>(bufA)[idx];
    uint4 ub = reinterpret_cast<const uint4*>(bufB)[idx];
    int ob = (idx & 1) * 8;
    const float4 b0 = reinterpret_cast<const float4*>(bias + ob)[0];
    const float4 b1 = reinterpret_cast<const float4*>(bias + ob + 4)[0];
    float fa[8], fb[8];
    u32 au[4] = {ua.x, ua.y, ua.z, ua.w}, bu[4] = {ub.x, ub.y, ub.z, ub.w};
#pragma unroll
    for (int j = 0; j < 4; ++j) {
        fa[2 * j]     = bfbits(au[j] << 16);
        fa[2 * j + 1] = bfbits(au[j] & 0xffff0000u);
        fb[2 * j]     = bfbits(bu[j] << 16);
        fb[2 * j + 1] = bfbits(bu[j] & 0xffff0000u);
    }
    float bb[8] = {b0.x, b0.y, b0.z, b0.w, b1.x, b1.y, b1.z, b1.w};
    float4 o0, o1;
    o0.x = fmaxf(fa[0] + fb[0] + bb[0], 0.f);
    o0.y = fmaxf(fa[1] + fb[1] + bb[1], 0.f);
    o0.z = fmaxf(fa[2] + fb[2] + bb[2], 0.f);
    o0.w = fmaxf(fa[3] + fb[3] + bb[3], 0.f);
    o1.x = fmaxf(fa[4] + fb[4] + bb[4], 0.f);
    o1.y = fmaxf(fa[5] + fb[5] + bb[5], 0.f);
    o1.z = fmaxf(fa[6] + fb[6] + bb[6], 0.f);
    o1.w = fmaxf(fa[7] + fb[7] + bb[7], 0.f);
    float4* op = reinterpret_cast<float4*>(out) + (size_t)idx * 2;
    op[0] = o0;
    op[1] = o1;
}

// ---------- fallback stage 2 (R6-proven): 16 lanes/edge, f32 atomics ----------
__global__ void __launch_bounds__(256) k_stage2(
    const int* __restrict__ ei, const float* __restrict__ ea,
    const u16* __restrict__ y, float* __restrict__ out,
    const int* __restrict__ flag, long long n_edges) {
    long long idx = (long long)blockIdx.x * 256 + threadIdx.x;
    if (idx >= n_edges * OUT_C) return;
    long long e = idx >> 4;
    int o = (int)(idx & 15);
    int src, dst;
    if (flag[0]) { src = ei[2 * e]; dst = ei[2 * (n_edges + e)]; }
    else         { src = ei[e];     dst = ei[n_edges + e]; }
    const float4* ap = reinterpret_cast<const float4*>(ea + e * NA);
    float4 a0 = ap[0], a1 = ap[1];
    uint4 yu = reinterpret_cast<const uint4*>(y + ((size_t)src * OUT_C + o) * NA)[0];
    float s = dot8y(yu, a0, a1);
    unsafeAtomicAdd(out + (size_t)dst * OUT_C + o, s);
}

__global__ void __launch_bounds__(256) k_bias_relu(
    const float* __restrict__ bias, float* __restrict__ out, int total4) {
    int idx = blockIdx.x * 256 + threadIdx.x;
    if (idx >= total4) return;
    int j0 = (idx & 3) * 4;
    const float4 b = reinterpret_cast<const float4*>(bias + j0)[0];
    float4* op = reinterpret_cast<float4*>(out) + idx;
    float4 v = op[0];
    v.x = fmaxf(v.x + b.x, 0.f);
    v.y = fmaxf(v.y + b.y, 0.f);
    v.z = fmaxf(v.z + b.z, 0.f);
    v.w = fmaxf(v.w + b.w, 0.f);
    op[0] = v;
}

// ---------- ultimate fallback (tiny ws): direct einsum, f32 atomics ----------
__global__ void __launch_bounds__(256) k_direct(
    const float* __restrict__ x, const int* __restrict__ ei,
    const float* __restrict__ ea, const float* __restrict__ W,
    float* __restrict__ out, long long n_edges) {
    __shared__ float Wl[OUT_C][129];
    for (int k = threadIdx.x; k < NA * OUT_C * IN_C; k += 256) {
        int a = k >> 8, o = (k >> 4) & 15, i = k & 15;
        Wl[o][a * IN_C + i] = W[k];
    }
    __syncthreads();
    long long idx = (long long)blockIdx.x * 256 + threadIdx.x;
    if (idx >= n_edges * OUT_C) return;
    long long e = idx >> 4;
    int o = (int)(idx & 15);
    int src = ei[2 * e], dst = ei[2 * (n_edges + e)];
    const float4* ap = reinterpret_cast<const float4*>(ea + e * NA);
    float4 a0 = ap[0], a1 = ap[1];
    float av[NA] = {a0.x, a0.y, a0.z, a0.w, a1.x, a1.y, a1.z, a1.w};
    const float4* xp = reinterpret_cast<const float4*>(x + (size_t)src * IN_C);
    float4 x0 = xp[0], x1 = xp[1], x2 = xp[2], x3 = xp[3];
    float xv[16] = {x0.x, x0.y, x0.z, x0.w, x1.x, x1.y, x1.z, x1.w,
                    x2.x, x2.y, x2.z, x2.w, x3.x, x3.y, x3.z, x3.w};
    float s = 0.f;
#pragma unroll
    for (int a = 0; a < NA; ++a) {
        float d = 0.f;
#pragma unroll
        for (int i = 0; i < IN_C; ++i) d = fmaf(Wl[o][a * IN_C + i], xv[i], d);
        s = fmaf(av[a], d, s);
    }
    unsafeAtomicAdd(out + (size_t)dst * OUT_C + o, s);
}

static inline size_t a256(size_t v) { return (v + 255) & ~(size_t)255; }

extern "C" void kernel_launch(void* const* d_in, const int* in_sizes, int n_in,
                              void* d_out, int out_size, void* d_ws, size_t ws_size,
                              hipStream_t stream) {
    const float* x    = (const float*)d_in[0];   // [N,16] f32
    const int*   ei   = (const int*)d_in[1];     // [2,E] int64/int32 (runtime-detected)
    const float* ea   = (const float*)d_in[2];   // [E,8] f32
    const float* W    = (const float*)d_in[3];   // [8,16,16] f32
    const float* bias = (const float*)d_in[4];   // [16] f32
    float* out = (float*)d_out;

    int n_nodes = in_sizes[0] / IN_C;
    long long E = in_sizes[2] / NA;

    size_t o_flag = 0;
    size_t o_y    = 256;
    size_t y_bytes = (size_t)n_nodes * OUT_C * NA * sizeof(u16);    // 25.6 MB
    size_t o_bufA = o_y + a256(y_bytes);
    size_t buf_bytes = (size_t)n_nodes * OUT_C * sizeof(u16);       // 3.2 MB each
    size_t o_bufB = o_bufA + a256(buf_bytes);
    size_t total_pk = o_bufB + a256(buf_bytes);                     // ~32.1 MB

    int npairs = (n_nodes + 1) >> 1;
    int g1 = (npairs * OUT_C + 255) / 256;

    if (ws_size >= total_pk) {
        int* flag = (int*)d_ws;
        u16* y    = (u16*)((char*)d_ws + o_y);
        u16* bufA = (u16*)((char*)d_ws + o_bufA);
        u16* bufB = (u16*)((char*)d_ws + o_bufB);
        // zero both bf16 accumulators (contiguous region)
        hipMemsetAsync((char*)d_ws + o_bufA, 0, a256(buf_bytes) + a256(buf_bytes), stream);
        k_stage1<<<g1, 256, 0, stream>>>(x, W, ei, E, y, out, flag, n_nodes);
        long long t2 = E * 8;
        k_stage2_pk<<<(int)((t2 + 255) / 256), 256, 0, stream>>>(ei, ea, y, bufA, bufB, flag, E);
        int t3 = (n_nodes * OUT_C) / 8;
        k_final_pk<<<(t3 + 255) / 256, 256, 0, stream>>>(bufA, bufB, bias, out, t3);
    } else if (ws_size >= 256 + y_bytes) {
        // R6-proven fallback: f32 atomics into d_out
        int* flag = (int*)d_ws;
        u16* y    = (u16*)((char*)d_ws + o_y);
        k_stage1<<<g1, 256, 0, stream>>>(x, W, ei, E, y, out, flag, n_nodes);
        long long tE = E * OUT_C;
        k_stage2<<<(int)((tE + 255) / 256), 256, 0, stream>>>(ei, ea, y, out, flag, E);
        int t4 = (n_nodes * OUT_C) / 4;
        k_bias_relu<<<(t4 + 255) / 256, 256, 0, stream>>>(bias, out, t4);
    } else {
        hipMemsetAsync(d_out, 0, (size_t)n_nodes * OUT_C * sizeof(float), stream);
        long long tE = E * OUT_C;
        k_direct<<<(int)((tE + 255) / 256), 256, 0, stream>>>(x, ei, ea, W, out, E);
        int t4 = (n_nodes * OUT_C) / 4;
        k_bias_relu<<<(t4 + 255) / 256, 256, 0, stream>>>(bias, out, t4);
    }
}